// Round 10
// baseline (206.899 us; speedup 1.0000x reference)
//
#include <hip/hip_runtime.h>
#include <math.h>

// Problem constants (from reference): B=16, Q=3000, C=1203
#define NB 16
#define NQR 3000
#define NC 1203

typedef float f32x4 __attribute__((ext_vector_type(4)));

// ---------------------------------------------------------------------------
// Decision math — FROZEN from round 3 (passed, absmax = 1 bf16 ulp).
// Fast path: hw exp + rcp, +/-1e-5 band; band elements redo the reference's
// exact f32 op-chain: f32(exp_f64(-x)), IEEE f32 add, IEEE f32 div.
// ---------------------------------------------------------------------------
__device__ __forceinline__ int lane_proc(float x, float t,
                                         float* __restrict__ s,
                                         float* __restrict__ k) {
    float pf = __builtin_amdgcn_rcpf(1.0f + __expf(-x));
    bool kp;
    float sc;
    if (pf > t + 1e-5f) {
        kp = true;  sc = pf;
    } else if (pf < t - 1e-5f) {
        kp = false; sc = 0.0f;
    } else {
        float e32 = (float)exp(-(double)x);   // correctly-rounded f32 exp
        float p32 = 1.0f / (1.0f + e32);      // IEEE f32 add + div
        kp = (p32 >= t);
        sc = kp ? p32 : 0.0f;
    }
    *s = sc;
    *k = kp ? 1.0f : 0.0f;
    return kp ? 1 : 0;
}

// ---------------------------------------------------------------------------
// Kernel 1: partial max of logits over a Q-chunk, per (b,c).
// grid: (ceil(C/256), B, nz), block 256. Lanes read adjacent c (coalesced);
// q-loop unrolled x8 -> 32 B/lane in flight.  [R5 structure, unchanged]
// ---------------------------------------------------------------------------
__global__ void k_partial_max(const float* __restrict__ logits,
                              float* __restrict__ partial,
                              int qc) {
    int c = blockIdx.x * blockDim.x + threadIdx.x;
    int b = blockIdx.y;
    int z = blockIdx.z;
    if (c >= NC) return;
    int q0 = z * qc;
    int q1 = min(NQR, q0 + qc);
    float m = -INFINITY;
    const float* p = logits + ((size_t)(b * NQR + q0)) * NC + c;
    int q = q0;
    for (; q + 8 <= q1; q += 8) {
        float a0 = p[0];
        float a1 = p[NC];
        float a2 = p[2 * NC];
        float a3 = p[3 * NC];
        float a4 = p[4 * NC];
        float a5 = p[5 * NC];
        float a6 = p[6 * NC];
        float a7 = p[7 * NC];
        float m01 = fmaxf(a0, a1), m23 = fmaxf(a2, a3);
        float m45 = fmaxf(a4, a5), m67 = fmaxf(a6, a7);
        m = fmaxf(m, fmaxf(fmaxf(m01, m23), fmaxf(m45, m67)));
        p += 8 * NC;
    }
    for (; q < q1; ++q) {
        m = fmaxf(m, *p);
        p += NC;
    }
    partial[((size_t)z * NB + b) * NC + c] = m;
}

// ---------------------------------------------------------------------------
// Kernel 2: combine partial maxes -> f32-chain threshold (frozen numerics).
// ---------------------------------------------------------------------------
__global__ void k_thresh(const float* __restrict__ partial,
                         const int* __restrict__ cls_present,
                         float* __restrict__ thrf,
                         int nz) {
    int c = blockIdx.x * blockDim.x + threadIdx.x;
    int b = blockIdx.y;
    if (c >= NC) return;
    float m = -INFINITY;
    for (int z = 0; z < nz; ++z)
        m = fmaxf(m, partial[((size_t)z * NB + b) * NC + c]);
    float t;
    if (cls_present[b * NC + c]) {
        float e32  = (float)exp(-(double)m);
        float ptop = 1.0f / (1.0f + e32);
        t = 0.5f * ptop;
    } else {
        t = INFINITY;
    }
    thrf[(size_t)b * NC + c] = t;
}

// ---------------------------------------------------------------------------
// Kernel 3: elementwise pass, ONE WAVE PER ROW (4 waves/block). R9 base with
// ONE change: PLAIN stores instead of nontemporal (A/B test — NT stores were
// in every wave-per-row run, never isolated; fill kernel proves plain stores
// hit 6.9 TB/s on this same buffer, while k_main runs at ~4 TB/s).
// LDS-staged thresholds kept (neutral at R9, saves global load issue slots).
// ---------------------------------------------------------------------------
__global__ __launch_bounds__(256) void k_main(const float* __restrict__ logits,
                                              const float* __restrict__ boxes,
                                              const float* __restrict__ thrf,
                                              float* __restrict__ scores,
                                              float* __restrict__ keep,
                                              float* __restrict__ boxes_out) {
    int wid  = threadIdx.x >> 6;
    int lane = threadIdx.x & 63;
    int row  = blockIdx.x * 4 + wid;          // grid sized exactly: 48000 rows
    int b    = row / NQR;                     // same for all 4 waves in block

    __shared__ float tsh[NC];
    {
        const float* tf = thrf + (size_t)b * NC;
        for (int i = threadIdx.x; i < NC; i += 256)
            tsh[i] = tf[i];
    }
    __syncthreads();

    const float* lrow = logits + (size_t)row * NC;
    float* srow = scores + (size_t)row * NC;
    float* krow = keep + (size_t)row * NC;

    int head = row & 3;
    int any = 0;
    float sv, kv;

    // head scalars (0..head-1)
    if (lane < head) {
        int c = lane;
        any |= lane_proc(lrow[c], tsh[c], &sv, &kv);
        srow[c] = sv;
        krow[c] = kv;
    }

    // aligned f32x4 body: 300 vectors (simple R5 loop, plain stores)
    for (int v = lane; v < 300; v += 64) {
        int c = head + 4 * v;
        f32x4 x4 = *(const f32x4*)(lrow + c);
        f32x4 s4, k4;
        float s0, s1, s2, s3, k0, k1, k2, k3;
        any |= lane_proc(x4.x, tsh[c + 0], &s0, &k0);
        any |= lane_proc(x4.y, tsh[c + 1], &s1, &k1);
        any |= lane_proc(x4.z, tsh[c + 2], &s2, &k2);
        any |= lane_proc(x4.w, tsh[c + 3], &s3, &k3);
        s4 = (f32x4){s0, s1, s2, s3};
        k4 = (f32x4){k0, k1, k2, k3};
        *(f32x4*)(srow + c) = s4;
        *(f32x4*)(krow + c) = k4;
    }

    // tail scalars (count = 3 - head)
    if (lane < 3 - head) {
        int c = head + 1200 + lane;
        any |= lane_proc(lrow[c], tsh[c], &sv, &kv);
        srow[c] = sv;
        krow[c] = kv;
    }

    unsigned long long m = __ballot(any);
    if (lane == 0) {
        float mm = m ? 1.0f : 0.0f;
        f32x4 bx = *(const f32x4*)(boxes + (size_t)row * 4);
        f32x4 o = bx * mm;
        *(f32x4*)(boxes_out + (size_t)row * 4) = o;
    }
}

extern "C" void kernel_launch(void* const* d_in, const int* in_sizes, int n_in,
                              void* d_out, int out_size, void* d_ws, size_t ws_size,
                              hipStream_t stream) {
    const float* logits      = (const float*)d_in[0];  // [B,Q,C] f32
    const float* boxes       = (const float*)d_in[1];  // [B,Q,4] f32
    // d_in[2] = target_sizes (unused by reference math)
    const int*   cls_present = (const int*)d_in[3];    // [B,C] 0/1

    float* scores    = (float*)d_out;                       // [B,Q,C]
    float* keep      = scores + (size_t)NB * NQR * NC;      // [B,Q,C]
    float* boxes_out = keep + (size_t)NB * NQR * NC;        // [B,Q,4]

    // Workspace layout: partial[nz][B][C] f32 | thrf[B][C] f32
    int nz = 25;
    while (nz > 1 && ((size_t)nz + 1) * NB * NC * sizeof(float) > ws_size)
        nz /= 2;
    float* partial = (float*)d_ws;
    float* thrf    = partial + (size_t)nz * NB * NC;
    int qc = (NQR + nz - 1) / nz;

    dim3 gmax((NC + 255) / 256, NB, nz);
    k_partial_max<<<gmax, 256, 0, stream>>>(logits, partial, qc);

    dim3 gthr((NC + 255) / 256, NB);
    k_thresh<<<gthr, 256, 0, stream>>>(partial, cls_present, thrf, nz);

    k_main<<<(NB * NQR) / 4, 256, 0, stream>>>(logits, boxes, thrf,
                                               scores, keep, boxes_out);
}

// Round 11
// 195.509 us; speedup vs baseline: 1.0583x; 1.0583x over previous
//
#include <hip/hip_runtime.h>
#include <math.h>

// Problem constants (from reference): B=16, Q=3000, C=1203
#define NB 16
#define NQR 3000
#define NC 1203

typedef float f32x4 __attribute__((ext_vector_type(4)));

// ---------------------------------------------------------------------------
// Decision math — FROZEN from round 3 (passed, absmax = 1 bf16 ulp).
// Fast path: hw exp + rcp, +/-1e-5 band; band elements redo the reference's
// exact f32 op-chain: f32(exp_f64(-x)), IEEE f32 add, IEEE f32 div.
// ---------------------------------------------------------------------------
__device__ __forceinline__ int lane_proc(float x, float t,
                                         float* __restrict__ s,
                                         float* __restrict__ k) {
    float pf = __builtin_amdgcn_rcpf(1.0f + __expf(-x));
    bool kp;
    float sc;
    if (pf > t + 1e-5f) {
        kp = true;  sc = pf;
    } else if (pf < t - 1e-5f) {
        kp = false; sc = 0.0f;
    } else {
        float e32 = (float)exp(-(double)x);   // correctly-rounded f32 exp
        float p32 = 1.0f / (1.0f + e32);      // IEEE f32 add + div
        kp = (p32 >= t);
        sc = kp ? p32 : 0.0f;
    }
    *s = sc;
    *k = kp ? 1.0f : 0.0f;
    return kp ? 1 : 0;
}

// ---------------------------------------------------------------------------
// Kernel 1: partial max of logits over a Q-chunk, per (b,c).
// grid: (ceil(C/256), B, nz), block 256. Lanes read adjacent c (coalesced);
// q-loop unrolled x8 -> 32 B/lane in flight.  [R5 structure, unchanged]
// ---------------------------------------------------------------------------
__global__ void k_partial_max(const float* __restrict__ logits,
                              float* __restrict__ partial,
                              int qc) {
    int c = blockIdx.x * blockDim.x + threadIdx.x;
    int b = blockIdx.y;
    int z = blockIdx.z;
    if (c >= NC) return;
    int q0 = z * qc;
    int q1 = min(NQR, q0 + qc);
    float m = -INFINITY;
    const float* p = logits + ((size_t)(b * NQR + q0)) * NC + c;
    int q = q0;
    for (; q + 8 <= q1; q += 8) {
        float a0 = p[0];
        float a1 = p[NC];
        float a2 = p[2 * NC];
        float a3 = p[3 * NC];
        float a4 = p[4 * NC];
        float a5 = p[5 * NC];
        float a6 = p[6 * NC];
        float a7 = p[7 * NC];
        float m01 = fmaxf(a0, a1), m23 = fmaxf(a2, a3);
        float m45 = fmaxf(a4, a5), m67 = fmaxf(a6, a7);
        m = fmaxf(m, fmaxf(fmaxf(m01, m23), fmaxf(m45, m67)));
        p += 8 * NC;
    }
    for (; q < q1; ++q) {
        m = fmaxf(m, *p);
        p += NC;
    }
    partial[((size_t)z * NB + b) * NC + c] = m;
}

// ---------------------------------------------------------------------------
// Kernel 2: combine partial maxes -> f32-chain threshold (frozen numerics).
// ---------------------------------------------------------------------------
__global__ void k_thresh(const float* __restrict__ partial,
                         const int* __restrict__ cls_present,
                         float* __restrict__ thrf,
                         int nz) {
    int c = blockIdx.x * blockDim.x + threadIdx.x;
    int b = blockIdx.y;
    if (c >= NC) return;
    float m = -INFINITY;
    for (int z = 0; z < nz; ++z)
        m = fmaxf(m, partial[((size_t)z * NB + b) * NC + c]);
    float t;
    if (cls_present[b * NC + c]) {
        float e32  = (float)exp(-(double)m);
        float ptop = 1.0f / (1.0f + e32);
        t = 0.5f * ptop;
    } else {
        t = INFINITY;
    }
    thrf[(size_t)b * NC + c] = t;
}

// ---------------------------------------------------------------------------
// Kernel 3: elementwise pass, ONE WAVE PER ROW (4 waves/block). Exact R9
// structure (NT stores — R10 proved them +16us; LDS thresholds; simple loop)
// with ONE change: LIFO row remap. Pass1 reads z-chunks in ascending order,
// so z=24 data is freshest in L3; k_main consumes (z desc, b, q) to hit the
// freshest lines first (LRU), instead of starting at the stalest (z=0).
// Mapping (nz==25, qc==120): bid -> zr=bid/480, b=(bid%480)/30, qb=bid%30,
// row = b*3000 + (24-zr)*120 + qb*4 + wid. Same b for all 4 waves of a
// block (LDS staging intact); row%4 == wid so head logic is unchanged.
// ---------------------------------------------------------------------------
__global__ __launch_bounds__(256) void k_main(const float* __restrict__ logits,
                                              const float* __restrict__ boxes,
                                              const float* __restrict__ thrf,
                                              float* __restrict__ scores,
                                              float* __restrict__ keep,
                                              float* __restrict__ boxes_out,
                                              int lifo) {
    int wid  = threadIdx.x >> 6;
    int lane = threadIdx.x & 63;
    int bid  = blockIdx.x;
    int row;
    if (lifo) {
        int zr  = bid / 480;            // 480 blocks per z-chunk (16 b * 30)
        int rem = bid - zr * 480;
        int b2  = rem / 30;
        int qb  = rem - b2 * 30;
        row = b2 * NQR + (24 - zr) * 120 + qb * 4 + wid;
    } else {
        row = bid * 4 + wid;
    }
    int b = row / NQR;                  // same for all 4 waves in block

    __shared__ float tsh[NC];
    {
        const float* tf = thrf + (size_t)b * NC;
        for (int i = threadIdx.x; i < NC; i += 256)
            tsh[i] = tf[i];
    }
    __syncthreads();

    const float* lrow = logits + (size_t)row * NC;
    float* srow = scores + (size_t)row * NC;
    float* krow = keep + (size_t)row * NC;

    int head = row & 3;
    int any = 0;
    float sv, kv;

    // head scalars (0..head-1)
    if (lane < head) {
        int c = lane;
        any |= lane_proc(lrow[c], tsh[c], &sv, &kv);
        __builtin_nontemporal_store(sv, srow + c);
        __builtin_nontemporal_store(kv, krow + c);
    }

    // aligned f32x4 body: 300 vectors (simple loop, NT stores)
    for (int v = lane; v < 300; v += 64) {
        int c = head + 4 * v;
        f32x4 x4 = *(const f32x4*)(lrow + c);
        f32x4 s4, k4;
        float s0, s1, s2, s3, k0, k1, k2, k3;
        any |= lane_proc(x4.x, tsh[c + 0], &s0, &k0);
        any |= lane_proc(x4.y, tsh[c + 1], &s1, &k1);
        any |= lane_proc(x4.z, tsh[c + 2], &s2, &k2);
        any |= lane_proc(x4.w, tsh[c + 3], &s3, &k3);
        s4 = (f32x4){s0, s1, s2, s3};
        k4 = (f32x4){k0, k1, k2, k3};
        __builtin_nontemporal_store(s4, (f32x4*)(srow + c));
        __builtin_nontemporal_store(k4, (f32x4*)(krow + c));
    }

    // tail scalars (count = 3 - head)
    if (lane < 3 - head) {
        int c = head + 1200 + lane;
        any |= lane_proc(lrow[c], tsh[c], &sv, &kv);
        __builtin_nontemporal_store(sv, srow + c);
        __builtin_nontemporal_store(kv, krow + c);
    }

    unsigned long long m = __ballot(any);
    if (lane == 0) {
        float mm = m ? 1.0f : 0.0f;
        f32x4 bx = *(const f32x4*)(boxes + (size_t)row * 4);
        f32x4 o = bx * mm;
        *(f32x4*)(boxes_out + (size_t)row * 4) = o;
    }
}

extern "C" void kernel_launch(void* const* d_in, const int* in_sizes, int n_in,
                              void* d_out, int out_size, void* d_ws, size_t ws_size,
                              hipStream_t stream) {
    const float* logits      = (const float*)d_in[0];  // [B,Q,C] f32
    const float* boxes       = (const float*)d_in[1];  // [B,Q,4] f32
    // d_in[2] = target_sizes (unused by reference math)
    const int*   cls_present = (const int*)d_in[3];    // [B,C] 0/1

    float* scores    = (float*)d_out;                       // [B,Q,C]
    float* keep      = scores + (size_t)NB * NQR * NC;      // [B,Q,C]
    float* boxes_out = keep + (size_t)NB * NQR * NC;        // [B,Q,4]

    // Workspace layout: partial[nz][B][C] f32 | thrf[B][C] f32
    int nz = 25;
    while (nz > 1 && ((size_t)nz + 1) * NB * NC * sizeof(float) > ws_size)
        nz /= 2;
    float* partial = (float*)d_ws;
    float* thrf    = partial + (size_t)nz * NB * NC;
    int qc = (NQR + nz - 1) / nz;

    dim3 gmax((NC + 255) / 256, NB, nz);
    k_partial_max<<<gmax, 256, 0, stream>>>(logits, partial, qc);

    dim3 gthr((NC + 255) / 256, NB);
    k_thresh<<<gthr, 256, 0, stream>>>(partial, cls_present, thrf, nz);

    int lifo = (nz == 25 && qc == 120) ? 1 : 0;
    k_main<<<(NB * NQR) / 4, 256, 0, stream>>>(logits, boxes, thrf,
                                               scores, keep, boxes_out, lifo);
}